// Round 3
// baseline (7734.711 us; speedup 1.0000x reference)
//
#include <hip/hip_runtime.h>
#include <math.h>

#define NB 32
#define NT 512
#define NDIN 1024
#define NDCB 256
#define NKCB 8192
#define NHMID 512
#define NROWS (NB*NT)   // 16384

// ---------------- fp64-accumulate tiled GEMM: C = act(A(MxK) * B(NxK)^T + bias) ----------------
// fp32 in/out, fp64 accumulation: output = fl(exact), the canonical fp32 result.
template<bool RELU>
__global__ __launch_bounds__(256) void gemm_nt_f64_kernel(
    const float* __restrict__ A, const float* __restrict__ Bm,
    const float* __restrict__ bias, float* __restrict__ C,
    int M, int N, int K)
{
    __shared__ double a_s[16*64];
    __shared__ double b_s[16*64];
    const int tid = threadIdx.x;
    const int bn0 = blockIdx.x * 64;
    const int bm0 = blockIdx.y * 64;
    const int lr = tid >> 2;          // 0..63
    const int kq = (tid & 3) << 2;    // 0,4,8,12
    const int tx = tid & 15, ty = tid >> 4;
    double acc[4][4] = {};
    const float* Ap = A + (size_t)(bm0 + lr) * K + kq;
    const float* Bp = Bm + (size_t)(bn0 + lr) * K + kq;
    for (int kt = 0; kt < K; kt += 16) {
        float4 a = *(const float4*)(Ap + kt);
        float4 b = *(const float4*)(Bp + kt);
        __syncthreads();
        a_s[(kq+0)*64+lr] = (double)a.x; a_s[(kq+1)*64+lr] = (double)a.y;
        a_s[(kq+2)*64+lr] = (double)a.z; a_s[(kq+3)*64+lr] = (double)a.w;
        b_s[(kq+0)*64+lr] = (double)b.x; b_s[(kq+1)*64+lr] = (double)b.y;
        b_s[(kq+2)*64+lr] = (double)b.z; b_s[(kq+3)*64+lr] = (double)b.w;
        __syncthreads();
        #pragma unroll
        for (int kk = 0; kk < 16; kk++) {
            double aa[4], bb[4];
            #pragma unroll
            for (int u = 0; u < 4; u++) { aa[u] = a_s[kk*64 + ty*4 + u]; bb[u] = b_s[kk*64 + tx*4 + u]; }
            #pragma unroll
            for (int i = 0; i < 4; i++)
                #pragma unroll
                for (int j = 0; j < 4; j++)
                    acc[i][j] = fma(aa[i], bb[j], acc[i][j]);
        }
    }
    const float4 b4 = *(const float4*)&bias[bn0 + tx*4];
    const double bc[4] = {(double)b4.x, (double)b4.y, (double)b4.z, (double)b4.w};
    #pragma unroll
    for (int i = 0; i < 4; i++) {
        float o[4];
        #pragma unroll
        for (int j = 0; j < 4; j++) {
            double v = acc[i][j] + bc[j];
            if (RELU) v = fmax(v, 0.0);
            o[j] = (float)v;
        }
        *(float4*)&C[(size_t)(bm0 + ty*4 + i)*N + bn0 + tx*4] =
            make_float4(o[0], o[1], o[2], o[3]);
    }
}

// ---------------- conv1d k=3 SAME, fp64 accumulation ----------------
__global__ __launch_bounds__(256) void conv3_f64_kernel(
    const float* __restrict__ H2, const float* __restrict__ W3,
    const float* __restrict__ bias, float* __restrict__ F)
{
    __shared__ double a_s[16*68];       // [k][local row], local l <-> global bm0-1+l
    __shared__ double b_s[3][16*64];
    const int tid = threadIdx.x;
    const int bn0 = blockIdx.x * 64;
    const int bm0 = blockIdx.y * 64;
    const int lr = tid >> 2;
    const int kq = (tid & 3) << 2;
    const int tx = tid & 15, ty = tid >> 4;
    const int tmod = bm0 & (NT-1);
    const bool has_top = (tmod != 0);
    const bool has_bot = (tmod + 64 < NT);
    double acc[4][4] = {};
    for (int kt = 0; kt < NDCB; kt += 16) {
        float4 a = make_float4(0.f,0.f,0.f,0.f);
        if (lr >= 1 || has_top)
            a = *(const float4*)&H2[(size_t)(bm0 - 1 + lr)*NDCB + kt + kq];
        float4 e = make_float4(0.f,0.f,0.f,0.f);
        int l2 = 0, kq2 = 0;
        if (tid < 8) {
            l2 = 64 + (tid >> 2); kq2 = (tid & 3) << 2;
            if (l2 == 64 || has_bot)
                e = *(const float4*)&H2[(size_t)(bm0 - 1 + l2)*NDCB + kt + kq2];
        }
        float4 w[3];
        #pragma unroll
        for (int s = 0; s < 3; s++)
            w[s] = *(const float4*)&W3[(size_t)s*65536 + (size_t)(bn0 + lr)*NDCB + kt + kq];
        __syncthreads();
        a_s[(kq+0)*68+lr]=(double)a.x; a_s[(kq+1)*68+lr]=(double)a.y;
        a_s[(kq+2)*68+lr]=(double)a.z; a_s[(kq+3)*68+lr]=(double)a.w;
        if (tid < 8) {
            a_s[(kq2+0)*68+l2]=(double)e.x; a_s[(kq2+1)*68+l2]=(double)e.y;
            a_s[(kq2+2)*68+l2]=(double)e.z; a_s[(kq2+3)*68+l2]=(double)e.w;
        }
        #pragma unroll
        for (int s = 0; s < 3; s++) {
            b_s[s][(kq+0)*64+lr]=(double)w[s].x; b_s[s][(kq+1)*64+lr]=(double)w[s].y;
            b_s[s][(kq+2)*64+lr]=(double)w[s].z; b_s[s][(kq+3)*64+lr]=(double)w[s].w;
        }
        __syncthreads();
        #pragma unroll
        for (int kk = 0; kk < 16; kk++) {
            double aa[6];
            #pragma unroll
            for (int u = 0; u < 6; u++) aa[u] = a_s[kk*68 + ty*4 + u];
            #pragma unroll
            for (int s = 0; s < 3; s++) {
                double bb[4];
                #pragma unroll
                for (int u = 0; u < 4; u++) bb[u] = b_s[s][kk*64 + tx*4 + u];
                #pragma unroll
                for (int i = 0; i < 4; i++)
                    #pragma unroll
                    for (int j = 0; j < 4; j++)
                        acc[i][j] = fma(aa[i+s], bb[j], acc[i][j]);
            }
        }
    }
    const float4 b4 = *(const float4*)&bias[bn0 + tx*4];
    const double bc[4] = {(double)b4.x, (double)b4.y, (double)b4.z, (double)b4.w};
    #pragma unroll
    for (int i = 0; i < 4; i++) {
        const size_t base = (size_t)(bm0 + ty*4 + i)*NDCB + bn0 + tx*4;
        *(float4*)&F[base] = make_float4((float)(acc[i][0]+bc[0]), (float)(acc[i][1]+bc[1]),
                                         (float)(acc[i][2]+bc[2]), (float)(acc[i][3]+bc[3]));
    }
}

// ---------------- VQ: fp32 GEMM prefilter + canonical-fp32-quantized argmin on near-ties ----
// Reference: d2 = fl32( fl32( s_f - 2*G ) + s_c ), argmin with first-index tie-break.
// fl32 is monotone => quantization only creates ties; tie-set = codes within 1 ulp(s_f~1.65)
// (1.19e-7) of the true min, covered by the 1e-6 prefilter window.
__global__ __launch_bounds__(512) void vq_kernel(
    const float* __restrict__ F, const float* __restrict__ CB,
    const float* __restrict__ cnorm, float* __restrict__ idx_out,
    float* __restrict__ qout, float* __restrict__ msd_acc)
{
    __shared__ float a_s[32*64];     // [k][row]   8 KB
    __shared__ float b_s[32*128];    // [k][col]  16 KB
    __shared__ float red_v[64*64];   // top-2 per (row, tx); reused for msd reduce
    __shared__ int   red_i[64*64];
    __shared__ int   bests[64];
    __shared__ int   cand[64][12];
    __shared__ int   ccnt[64];
    const int tid = threadIdx.x;
    const int m0 = blockIdx.x * 64;
    const int tx = tid & 31, ty = tid >> 5;   // 32 x 16
    float mv1[4], mv2[4]; int mi1[4], mi2[4];
    #pragma unroll
    for (int i = 0; i < 4; i++) { mv1[i]=3.0e38f; mv2[i]=3.0e38f; mi1[i]=0x7fffffff; mi2[i]=0x7fffffff; }
    const int ar  = tid >> 3;            // 0..63
    const int akq = (tid & 7) << 2;      // 0..28
    for (int n0 = 0; n0 < NKCB; n0 += 128) {
        float dot[4][4] = {};
        for (int kt = 0; kt < NDCB; kt += 32) {
            __syncthreads();
            {
                float4 a = *(const float4*)&F[(size_t)(m0 + ar)*NDCB + kt + akq];
                a_s[(akq+0)*64+ar]=a.x; a_s[(akq+1)*64+ar]=a.y;
                a_s[(akq+2)*64+ar]=a.z; a_s[(akq+3)*64+ar]=a.w;
            }
            #pragma unroll
            for (int u = 0; u < 2; u++) {
                int e2 = tid + u*512;
                int c = e2 >> 3, kqb = (e2 & 7) << 2;
                float4 b = *(const float4*)&CB[(size_t)(n0 + c)*NDCB + kt + kqb];
                b_s[(kqb+0)*128+c]=b.x; b_s[(kqb+1)*128+c]=b.y;
                b_s[(kqb+2)*128+c]=b.z; b_s[(kqb+3)*128+c]=b.w;
            }
            __syncthreads();
            #pragma unroll
            for (int kk = 0; kk < 32; kk++) {
                const float4 av = *(const float4*)&a_s[kk*64 + ty*4];
                const float4 bv = *(const float4*)&b_s[kk*128 + tx*4];
                const float aa[4]={av.x,av.y,av.z,av.w};
                const float bb[4]={bv.x,bv.y,bv.z,bv.w};
                #pragma unroll
                for (int i=0;i<4;i++)
                    #pragma unroll
                    for (int j=0;j<4;j++)
                        dot[i][j] = fmaf(aa[i], bb[j], dot[i][j]);
            }
        }
        #pragma unroll
        for (int j = 0; j < 4; j++) {
            const int col = n0 + tx*4 + j;
            const float cn = cnorm[col];
            #pragma unroll
            for (int i = 0; i < 4; i++) {
                float s = fmaf(-2.0f, dot[i][j], cn);
                if (s < mv1[i]) { mv2[i]=mv1[i]; mi2[i]=mi1[i]; mv1[i]=s; mi1[i]=col; }
                else if (s < mv2[i]) { mv2[i]=s; mi2[i]=col; }
            }
        }
    }
    #pragma unroll
    for (int i = 0; i < 4; i++) {
        const int row = ty*4 + i;
        red_v[row*64 + tx*2 + 0] = mv1[i]; red_i[row*64 + tx*2 + 0] = mi1[i];
        red_v[row*64 + tx*2 + 1] = mv2[i]; red_i[row*64 + tx*2 + 1] = mi2[i];
    }
    __syncthreads();
    if (tid < 64) {
        float bv = 3.0e38f; int bi = 0x7fffffff;
        for (int e = 0; e < 64; e++) {
            float v = red_v[tid*64 + e]; int ii = red_i[tid*64 + e];
            if (v < bv || (v == bv && ii < bi)) { bv = v; bi = ii; }
        }
        int cnt = 0;
        for (int e = 0; e < 64; e++) {
            if (red_v[tid*64 + e] < bv + 1.0e-6f) {
                if (cnt < 12) cand[tid][cnt] = red_i[tid*64 + e];
                cnt++;
            }
        }
        bests[tid] = bi;
        ccnt[tid] = (cnt > 12) ? 12 : cnt;
    }
    __syncthreads();
    // Canonical fp32-quantized rescore of near-tie rows (one wave per row, round-robin).
    {
        const int wid = tid >> 6, lane = tid & 63;
        for (int r = wid; r < 64; r += 8) {
            const int nc = ccnt[r];
            if (nc < 2) continue;
            // s_f = fl32(sum f^2), computed exactly in fp64
            double sf = 0.0;
            #pragma unroll
            for (int u = 0; u < 4; u++) {
                double fv = (double)F[(size_t)(m0+r)*NDCB + lane*4 + u];
                sf = fma(fv, fv, sf);
            }
            #pragma unroll
            for (int off = 32; off > 0; off >>= 1) sf += __shfl_down(sf, off);
            const float sf32 = (float)sf;          // valid on lane 0
            float bd2 = 0.0f; int bidx = 0x7fffffff;
            for (int c = 0; c < nc; c++) {
                const int k = cand[r][c];
                double g = 0.0;
                #pragma unroll
                for (int u = 0; u < 4; u++) {
                    double cv = (double)CB[(size_t)k*NDCB + lane*4 + u];
                    double fv = (double)F[(size_t)(m0+r)*NDCB + lane*4 + u];
                    g = fma(cv, fv, g);
                }
                #pragma unroll
                for (int off = 32; off > 0; off >>= 1) g += __shfl_down(g, off);
                if (lane == 0) {
                    const float G32 = (float)g;
                    const float t  = sf32 - 2.0f*G32;   // *2 exact; single fp32 rounding
                    const float d2 = t + cnorm[k];      // second fp32 rounding
                    if (c == 0 || d2 < bd2 || (d2 == bd2 && k < bidx)) { bd2 = d2; bidx = k; }
                }
            }
            if (lane == 0) bests[r] = bidx;
        }
    }
    __syncthreads();
    if (tid < 64) idx_out[m0 + tid] = (float)bests[tid];
    float lsum = 0.0f;
    #pragma unroll
    for (int s = 0; s < 8; s++) {
        int e = tid + s*512;                 // float4 index over 64*256/4 = 4096
        int row = e >> 6, kqe = (e & 63) << 2;
        float4 q = *(const float4*)&CB[(size_t)bests[row]*NDCB + kqe];
        float4 f = *(const float4*)&F[(size_t)(m0+row)*NDCB + kqe];
        float dx=f.x-q.x, dy=f.y-q.y, dz=f.z-q.z, dw=f.w-q.w;
        lsum += dx*dx + dy*dy + dz*dz + dw*dw;
        *(float4*)&qout[(size_t)(m0+row)*NDCB + kqe] = q;
    }
    red_v[tid] = lsum;
    __syncthreads();
    for (int off = 256; off > 0; off >>= 1) {
        if (tid < off) red_v[tid] += red_v[tid + off];
        __syncthreads();
    }
    if (tid == 0) atomicAdd(msd_acc, red_v[0]);
}

// ---------------- fp32 tiled GEMM for xproj (feeds GRU/context_loss, 2% threshold) ------------
__global__ __launch_bounds__(256) void gemm_nt_kernel(
    const float* __restrict__ A, const float* __restrict__ Bm,
    const float* __restrict__ bias, float* __restrict__ C,
    int M, int N, int K)
{
    __shared__ float a_s[16*64];
    __shared__ float b_s[16*64];
    const int tid = threadIdx.x;
    const int bn0 = blockIdx.x * 64;
    const int bm0 = blockIdx.y * 64;
    const int lr = tid >> 2;
    const int kq = (tid & 3) << 2;
    const int tx = tid & 15, ty = tid >> 4;
    float acc[4][4] = {};
    const float* Ap = A + (size_t)(bm0 + lr) * K + kq;
    const float* Bp = Bm + (size_t)(bn0 + lr) * K + kq;
    for (int kt = 0; kt < K; kt += 16) {
        float4 a = *(const float4*)(Ap + kt);
        float4 b = *(const float4*)(Bp + kt);
        __syncthreads();
        a_s[(kq+0)*64+lr] = a.x; a_s[(kq+1)*64+lr] = a.y;
        a_s[(kq+2)*64+lr] = a.z; a_s[(kq+3)*64+lr] = a.w;
        b_s[(kq+0)*64+lr] = b.x; b_s[(kq+1)*64+lr] = b.y;
        b_s[(kq+2)*64+lr] = b.z; b_s[(kq+3)*64+lr] = b.w;
        __syncthreads();
        #pragma unroll
        for (int kk = 0; kk < 16; kk++) {
            const float4 av = *(const float4*)&a_s[kk*64 + ty*4];
            const float4 bv = *(const float4*)&b_s[kk*64 + tx*4];
            const float aa[4] = {av.x, av.y, av.z, av.w};
            const float bb[4] = {bv.x, bv.y, bv.z, bv.w};
            #pragma unroll
            for (int i = 0; i < 4; i++)
                #pragma unroll
                for (int j = 0; j < 4; j++)
                    acc[i][j] = fmaf(aa[i], bb[j], acc[i][j]);
        }
    }
    const float4 b4 = *(const float4*)&bias[bn0 + tx*4];
    const float bc[4] = {b4.x, b4.y, b4.z, b4.w};
    #pragma unroll
    for (int i = 0; i < 4; i++) {
        *(float4*)&C[(size_t)(bm0 + ty*4 + i)*N + bn0 + tx*4] =
            make_float4(acc[i][0]+bc[0], acc[i][1]+bc[1], acc[i][2]+bc[2], acc[i][3]+bc[3]);
    }
}

// ---------------- GRU scan: one workgroup per batch element ----------------
__global__ __launch_bounds__(256) void gru_kernel(
    const float* __restrict__ XP, const float* __restrict__ WT,
    const float* __restrict__ bhh, const float* __restrict__ F,
    float* __restrict__ ctx_acc)
{
    __shared__ float hbuf[2][256];
    __shared__ float red[256];
    const int tid = threadIdx.x;
    const int b = blockIdx.x;
    hbuf[0][tid] = 0.0f;
    const float bb0 = bhh[tid], bb1 = bhh[256+tid], bb2 = bhh[512+tid];
    const float* w0 = WT + tid;
    const float* w1 = WT + 256 + tid;
    const float* w2 = WT + 512 + tid;
    float lsum = 0.0f;
    __syncthreads();
    int cur = 0;
    for (int t = 0; t < NT-1; t++) {
        const float* hc = hbuf[cur];
        float a0 = bb0, a1 = bb1, a2 = bb2;
        #pragma unroll 8
        for (int i = 0; i < 256; i++) {
            float hv = hc[i];
            a0 = fmaf(w0[i*768], hv, a0);
            a1 = fmaf(w1[i*768], hv, a1);
            a2 = fmaf(w2[i*768], hv, a2);
        }
        const float* xp = XP + ((size_t)b*NT + t)*768;
        float r = 1.0f/(1.0f + __expf(-(xp[tid] + a0)));
        float z = 1.0f/(1.0f + __expf(-(xp[256+tid] + a1)));
        float n = tanhf(fmaf(r, a2, xp[512+tid]));
        float hnew = (1.0f - z)*n + z*hc[tid];
        float fv = F[((size_t)b*NT + t + 1)*NDCB + tid];
        float d = hnew - fv;
        lsum = fmaf(d, d, lsum);
        hbuf[cur^1][tid] = hnew;
        __syncthreads();
        cur ^= 1;
    }
    red[tid] = lsum;
    __syncthreads();
    for (int off = 128; off > 0; off >>= 1) {
        if (tid < off) red[tid] += red[tid+off];
        __syncthreads();
    }
    if (tid == 0) atomicAdd(ctx_acc, red[0]);
}

// ---------------- small prep kernels ----------------
__global__ __launch_bounds__(256) void prep_kernel(
    const float* __restrict__ conv_w, float* __restrict__ w3,
    const float* __restrict__ whh, float* __restrict__ wht,
    float* __restrict__ accv)
{
    int e = blockIdx.x*256 + threadIdx.x;     // < 196608
    if (e == 0) { accv[0] = 0.0f; accv[1] = 0.0f; }
    {   // w3[k][c][i] = conv_w[c][i][k]
        int k = e >> 16;
        int r = e & 65535;
        int c = r >> 8, i = r & 255;
        w3[e] = conv_w[(size_t)c*768 + i*3 + k];
    }
    {   // wht[i][j] = whh[j][i]
        int i = e / 768, j = e - i*768;
        wht[e] = whh[(size_t)j*256 + i];
    }
}

// s_c = fl32(exact sum c^2) via fp64
__global__ __launch_bounds__(64) void cnorm_kernel(
    const float* __restrict__ CB, float* __restrict__ cn)
{
    const int k = blockIdx.x;
    const int lane = threadIdx.x;
    float4 v = *(const float4*)&CB[(size_t)k*NDCB + lane*4];
    double s = (double)v.x*(double)v.x + (double)v.y*(double)v.y
             + (double)v.z*(double)v.z + (double)v.w*(double)v.w;
    #pragma unroll
    for (int off = 32; off > 0; off >>= 1) s += __shfl_down(s, off);
    if (lane == 0) cn[k] = (float)s;
}

__global__ void finalize_kernel(const float* __restrict__ acc, float* __restrict__ out)
{
    if (threadIdx.x == 0) {
        float msd = acc[0] * (1.0f/4194304.0f);   // mean over 32*512*256
        float ctx = acc[1] * (1.0f/4184064.0f);   // mean over 32*511*256
        out[0] = msd;                 // commitment_loss
        out[1] = msd;                 // codebook_loss (same forward value)
        out[2] = ctx;                 // context_loss
        out[3] = 1.25f*msd + 0.1f*ctx; // vq_loss
    }
}

extern "C" void kernel_launch(void* const* d_in, const int* in_sizes, int n_in,
                              void* d_out, int out_size, void* d_ws, size_t ws_size,
                              hipStream_t stream) {
    const float* x      = (const float*)d_in[0];
    const float* w1     = (const float*)d_in[1];
    const float* b1     = (const float*)d_in[2];
    const float* w2     = (const float*)d_in[3];
    const float* b2     = (const float*)d_in[4];
    const float* conv_w = (const float*)d_in[5];
    const float* conv_b = (const float*)d_in[6];
    const float* cb     = (const float*)d_in[7];
    const float* wih    = (const float*)d_in[8];
    const float* whh    = (const float*)d_in[9];
    const float* bih    = (const float*)d_in[10];
    const float* bhh    = (const float*)d_in[11];
    float* out = (float*)d_out;

    // workspace layout (regions re-used once dead):
    //   [0,        16.7M)  feat  (fp32)          conv -> gru
    //   [16.7M,    50.3M)  h1    (fp32)          gemm1 -> gemm2
    //   [16.7M,    67.1M)  xproj (fp32, 50.3MB)  gemm3 -> gru   (overlays dead h1+h2)
    //   [50.3M,    67.1M)  h2    (fp32)          gemm2 -> conv
    //   [67.1M, ...]       cn / w3 / wht / accv
    char* ws = (char*)d_ws;
    float*  feat   = (float*)(ws + 0);
    float*  h1     = (float*)(ws + 16777216);
    float*  xproj  = (float*)(ws + 16777216);
    float*  h2     = (float*)(ws + 50331648);
    float*  cn     = (float*)(ws + 67108864);
    float*  w3     = (float*)(ws + 67141632);
    float*  wht    = (float*)(ws + 67928064);
    float*  accv   = (float*)(ws + 68714496);

    float* idx_out = out;                   // 16384 indices (as float)
    float* qout    = out + 16384;           // 4,194,304 quantized
    float* louts   = out + 16384 + 4194304; // 4 scalars

    prep_kernel<<<768, 256, 0, stream>>>(conv_w, w3, whh, wht, accv);
    cnorm_kernel<<<NKCB, 64, 0, stream>>>(cb, cn);
    gemm_nt_f64_kernel<true ><<<dim3(NHMID/64, NROWS/64), 256, 0, stream>>>(x,  w1, b1, h1, NROWS, NHMID, NDIN);
    gemm_nt_f64_kernel<true ><<<dim3(NDCB/64,  NROWS/64), 256, 0, stream>>>(h1, w2, b2, h2, NROWS, NDCB, NHMID);
    conv3_f64_kernel<<<dim3(NDCB/64, NROWS/64), 256, 0, stream>>>(h2, w3, conv_b, feat);
    vq_kernel<<<NROWS/64, 512, 0, stream>>>(feat, cb, cn, idx_out, qout, accv);
    gemm_nt_kernel<<<dim3(768/64, NROWS/64), 256, 0, stream>>>(qout, wih, bih, xproj, NROWS, 768, NDCB);
    gru_kernel<<<NB, 256, 0, stream>>>(xproj, wht, bhh, feat, accv + 1);
    finalize_kernel<<<1, 64, 0, stream>>>(accv, louts);
}

// Round 4
// 6965.306 us; speedup vs baseline: 1.1105x; 1.1105x over previous
//
#include <hip/hip_runtime.h>
#include <math.h>

#define NB 32
#define NT 512
#define NDIN 1024
#define NDCB 256
#define NKCB 8192
#define NHMID 512
#define NROWS (NB*NT)   // 16384

// ---------------- fp64-accumulate tiled GEMM: C = act(A(MxK) * B(NxK)^T + bias) ----------------
// fp32 in/out, fp64 accumulation: output = fl(exact), the canonical fp32 result.  [LOCKED numerics]
template<bool RELU>
__global__ __launch_bounds__(256) void gemm_nt_f64_kernel(
    const float* __restrict__ A, const float* __restrict__ Bm,
    const float* __restrict__ bias, float* __restrict__ C,
    int M, int N, int K)
{
    __shared__ double a_s[16*64];
    __shared__ double b_s[16*64];
    const int tid = threadIdx.x;
    const int bn0 = blockIdx.x * 64;
    const int bm0 = blockIdx.y * 64;
    const int lr = tid >> 2;          // 0..63
    const int kq = (tid & 3) << 2;    // 0,4,8,12
    const int tx = tid & 15, ty = tid >> 4;
    double acc[4][4] = {};
    const float* Ap = A + (size_t)(bm0 + lr) * K + kq;
    const float* Bp = Bm + (size_t)(bn0 + lr) * K + kq;
    for (int kt = 0; kt < K; kt += 16) {
        float4 a = *(const float4*)(Ap + kt);
        float4 b = *(const float4*)(Bp + kt);
        __syncthreads();
        a_s[(kq+0)*64+lr] = (double)a.x; a_s[(kq+1)*64+lr] = (double)a.y;
        a_s[(kq+2)*64+lr] = (double)a.z; a_s[(kq+3)*64+lr] = (double)a.w;
        b_s[(kq+0)*64+lr] = (double)b.x; b_s[(kq+1)*64+lr] = (double)b.y;
        b_s[(kq+2)*64+lr] = (double)b.z; b_s[(kq+3)*64+lr] = (double)b.w;
        __syncthreads();
        #pragma unroll
        for (int kk = 0; kk < 16; kk++) {
            double aa[4], bb[4];
            #pragma unroll
            for (int u = 0; u < 4; u++) { aa[u] = a_s[kk*64 + ty*4 + u]; bb[u] = b_s[kk*64 + tx*4 + u]; }
            #pragma unroll
            for (int i = 0; i < 4; i++)
                #pragma unroll
                for (int j = 0; j < 4; j++)
                    acc[i][j] = fma(aa[i], bb[j], acc[i][j]);
        }
    }
    const float4 b4 = *(const float4*)&bias[bn0 + tx*4];
    const double bc[4] = {(double)b4.x, (double)b4.y, (double)b4.z, (double)b4.w};
    #pragma unroll
    for (int i = 0; i < 4; i++) {
        float o[4];
        #pragma unroll
        for (int j = 0; j < 4; j++) {
            double v = acc[i][j] + bc[j];
            if (RELU) v = fmax(v, 0.0);
            o[j] = (float)v;
        }
        *(float4*)&C[(size_t)(bm0 + ty*4 + i)*N + bn0 + tx*4] =
            make_float4(o[0], o[1], o[2], o[3]);
    }
}

// ---------------- conv1d k=3 SAME, fp64 accumulation ----------------  [LOCKED numerics]
__global__ __launch_bounds__(256) void conv3_f64_kernel(
    const float* __restrict__ H2, const float* __restrict__ W3,
    const float* __restrict__ bias, float* __restrict__ F)
{
    __shared__ double a_s[16*68];       // [k][local row], local l <-> global bm0-1+l
    __shared__ double b_s[3][16*64];
    const int tid = threadIdx.x;
    const int bn0 = blockIdx.x * 64;
    const int bm0 = blockIdx.y * 64;
    const int lr = tid >> 2;
    const int kq = (tid & 3) << 2;
    const int tx = tid & 15, ty = tid >> 4;
    const int tmod = bm0 & (NT-1);
    const bool has_top = (tmod != 0);
    const bool has_bot = (tmod + 64 < NT);
    double acc[4][4] = {};
    for (int kt = 0; kt < NDCB; kt += 16) {
        float4 a = make_float4(0.f,0.f,0.f,0.f);
        if (lr >= 1 || has_top)
            a = *(const float4*)&H2[(size_t)(bm0 - 1 + lr)*NDCB + kt + kq];
        float4 e = make_float4(0.f,0.f,0.f,0.f);
        int l2 = 0, kq2 = 0;
        if (tid < 8) {
            l2 = 64 + (tid >> 2); kq2 = (tid & 3) << 2;
            if (l2 == 64 || has_bot)
                e = *(const float4*)&H2[(size_t)(bm0 - 1 + l2)*NDCB + kt + kq2];
        }
        float4 w[3];
        #pragma unroll
        for (int s = 0; s < 3; s++)
            w[s] = *(const float4*)&W3[(size_t)s*65536 + (size_t)(bn0 + lr)*NDCB + kt + kq];
        __syncthreads();
        a_s[(kq+0)*68+lr]=(double)a.x; a_s[(kq+1)*68+lr]=(double)a.y;
        a_s[(kq+2)*68+lr]=(double)a.z; a_s[(kq+3)*68+lr]=(double)a.w;
        if (tid < 8) {
            a_s[(kq2+0)*68+l2]=(double)e.x; a_s[(kq2+1)*68+l2]=(double)e.y;
            a_s[(kq2+2)*68+l2]=(double)e.z; a_s[(kq2+3)*68+l2]=(double)e.w;
        }
        #pragma unroll
        for (int s = 0; s < 3; s++) {
            b_s[s][(kq+0)*64+lr]=(double)w[s].x; b_s[s][(kq+1)*64+lr]=(double)w[s].y;
            b_s[s][(kq+2)*64+lr]=(double)w[s].z; b_s[s][(kq+3)*64+lr]=(double)w[s].w;
        }
        __syncthreads();
        #pragma unroll
        for (int kk = 0; kk < 16; kk++) {
            double aa[6];
            #pragma unroll
            for (int u = 0; u < 6; u++) aa[u] = a_s[kk*68 + ty*4 + u];
            #pragma unroll
            for (int s = 0; s < 3; s++) {
                double bb[4];
                #pragma unroll
                for (int u = 0; u < 4; u++) bb[u] = b_s[s][kk*64 + tx*4 + u];
                #pragma unroll
                for (int i = 0; i < 4; i++)
                    #pragma unroll
                    for (int j = 0; j < 4; j++)
                        acc[i][j] = fma(aa[i+s], bb[j], acc[i][j]);
            }
        }
    }
    const float4 b4 = *(const float4*)&bias[bn0 + tx*4];
    const double bc[4] = {(double)b4.x, (double)b4.y, (double)b4.z, (double)b4.w};
    #pragma unroll
    for (int i = 0; i < 4; i++) {
        const size_t base = (size_t)(bm0 + ty*4 + i)*NDCB + bn0 + tx*4;
        *(float4*)&F[base] = make_float4((float)(acc[i][0]+bc[0]), (float)(acc[i][1]+bc[1]),
                                         (float)(acc[i][2]+bc[2]), (float)(acc[i][3]+bc[3]));
    }
}

// ---------------- VQ: fp32 GEMM prefilter + canonical-fp32-quantized argmin on near-ties ----
// [LOCKED numerics] d2 = fl32( fl32( s_f - 2*G ) + s_c ), argmin with first-index tie-break.
__global__ __launch_bounds__(512) void vq_kernel(
    const float* __restrict__ F, const float* __restrict__ CB,
    const float* __restrict__ cnorm, float* __restrict__ idx_out,
    float* __restrict__ qout, float* __restrict__ msd_acc)
{
    __shared__ float a_s[32*64];     // [k][row]   8 KB
    __shared__ float b_s[32*128];    // [k][col]  16 KB
    __shared__ float red_v[64*64];   // top-2 per (row, tx); reused for msd reduce
    __shared__ int   red_i[64*64];
    __shared__ int   bests[64];
    __shared__ int   cand[64][12];
    __shared__ int   ccnt[64];
    const int tid = threadIdx.x;
    const int m0 = blockIdx.x * 64;
    const int tx = tid & 31, ty = tid >> 5;   // 32 x 16
    float mv1[4], mv2[4]; int mi1[4], mi2[4];
    #pragma unroll
    for (int i = 0; i < 4; i++) { mv1[i]=3.0e38f; mv2[i]=3.0e38f; mi1[i]=0x7fffffff; mi2[i]=0x7fffffff; }
    const int ar  = tid >> 3;            // 0..63
    const int akq = (tid & 7) << 2;      // 0..28
    for (int n0 = 0; n0 < NKCB; n0 += 128) {
        float dot[4][4] = {};
        for (int kt = 0; kt < NDCB; kt += 32) {
            __syncthreads();
            {
                float4 a = *(const float4*)&F[(size_t)(m0 + ar)*NDCB + kt + akq];
                a_s[(akq+0)*64+ar]=a.x; a_s[(akq+1)*64+ar]=a.y;
                a_s[(akq+2)*64+ar]=a.z; a_s[(akq+3)*64+ar]=a.w;
            }
            #pragma unroll
            for (int u = 0; u < 2; u++) {
                int e2 = tid + u*512;
                int c = e2 >> 3, kqb = (e2 & 7) << 2;
                float4 b = *(const float4*)&CB[(size_t)(n0 + c)*NDCB + kt + kqb];
                b_s[(kqb+0)*128+c]=b.x; b_s[(kqb+1)*128+c]=b.y;
                b_s[(kqb+2)*128+c]=b.z; b_s[(kqb+3)*128+c]=b.w;
            }
            __syncthreads();
            #pragma unroll
            for (int kk = 0; kk < 32; kk++) {
                const float4 av = *(const float4*)&a_s[kk*64 + ty*4];
                const float4 bv = *(const float4*)&b_s[kk*128 + tx*4];
                const float aa[4]={av.x,av.y,av.z,av.w};
                const float bb[4]={bv.x,bv.y,bv.z,bv.w};
                #pragma unroll
                for (int i=0;i<4;i++)
                    #pragma unroll
                    for (int j=0;j<4;j++)
                        dot[i][j] = fmaf(aa[i], bb[j], dot[i][j]);
            }
        }
        #pragma unroll
        for (int j = 0; j < 4; j++) {
            const int col = n0 + tx*4 + j;
            const float cn = cnorm[col];
            #pragma unroll
            for (int i = 0; i < 4; i++) {
                float s = fmaf(-2.0f, dot[i][j], cn);
                if (s < mv1[i]) { mv2[i]=mv1[i]; mi2[i]=mi1[i]; mv1[i]=s; mi1[i]=col; }
                else if (s < mv2[i]) { mv2[i]=s; mi2[i]=col; }
            }
        }
    }
    #pragma unroll
    for (int i = 0; i < 4; i++) {
        const int row = ty*4 + i;
        red_v[row*64 + tx*2 + 0] = mv1[i]; red_i[row*64 + tx*2 + 0] = mi1[i];
        red_v[row*64 + tx*2 + 1] = mv2[i]; red_i[row*64 + tx*2 + 1] = mi2[i];
    }
    __syncthreads();
    if (tid < 64) {
        float bv = 3.0e38f; int bi = 0x7fffffff;
        for (int e = 0; e < 64; e++) {
            float v = red_v[tid*64 + e]; int ii = red_i[tid*64 + e];
            if (v < bv || (v == bv && ii < bi)) { bv = v; bi = ii; }
        }
        int cnt = 0;
        for (int e = 0; e < 64; e++) {
            if (red_v[tid*64 + e] < bv + 1.0e-6f) {
                if (cnt < 12) cand[tid][cnt] = red_i[tid*64 + e];
                cnt++;
            }
        }
        bests[tid] = bi;
        ccnt[tid] = (cnt > 12) ? 12 : cnt;
    }
    __syncthreads();
    // Canonical fp32-quantized rescore of near-tie rows (one wave per row, round-robin).
    {
        const int wid = tid >> 6, lane = tid & 63;
        for (int r = wid; r < 64; r += 8) {
            const int nc = ccnt[r];
            if (nc < 2) continue;
            double sf = 0.0;
            #pragma unroll
            for (int u = 0; u < 4; u++) {
                double fv = (double)F[(size_t)(m0+r)*NDCB + lane*4 + u];
                sf = fma(fv, fv, sf);
            }
            #pragma unroll
            for (int off = 32; off > 0; off >>= 1) sf += __shfl_down(sf, off);
            const float sf32 = (float)sf;          // valid on lane 0
            float bd2 = 0.0f; int bidx = 0x7fffffff;
            for (int c = 0; c < nc; c++) {
                const int k = cand[r][c];
                double g = 0.0;
                #pragma unroll
                for (int u = 0; u < 4; u++) {
                    double cv = (double)CB[(size_t)k*NDCB + lane*4 + u];
                    double fv = (double)F[(size_t)(m0+r)*NDCB + lane*4 + u];
                    g = fma(cv, fv, g);
                }
                #pragma unroll
                for (int off = 32; off > 0; off >>= 1) g += __shfl_down(g, off);
                if (lane == 0) {
                    const float G32 = (float)g;
                    const float t  = sf32 - 2.0f*G32;
                    const float d2 = t + cnorm[k];
                    if (c == 0 || d2 < bd2 || (d2 == bd2 && k < bidx)) { bd2 = d2; bidx = k; }
                }
            }
            if (lane == 0) bests[r] = bidx;
        }
    }
    __syncthreads();
    if (tid < 64) idx_out[m0 + tid] = (float)bests[tid];
    float lsum = 0.0f;
    #pragma unroll
    for (int s = 0; s < 8; s++) {
        int e = tid + s*512;
        int row = e >> 6, kqe = (e & 63) << 2;
        float4 q = *(const float4*)&CB[(size_t)bests[row]*NDCB + kqe];
        float4 f = *(const float4*)&F[(size_t)(m0+row)*NDCB + kqe];
        float dx=f.x-q.x, dy=f.y-q.y, dz=f.z-q.z, dw=f.w-q.w;
        lsum += dx*dx + dy*dy + dz*dz + dw*dw;
        *(float4*)&qout[(size_t)(m0+row)*NDCB + kqe] = q;
    }
    red_v[tid] = lsum;
    __syncthreads();
    for (int off = 256; off > 0; off >>= 1) {
        if (tid < off) red_v[tid] += red_v[tid + off];
        __syncthreads();
    }
    if (tid == 0) atomicAdd(msd_acc, red_v[0]);
}

// ---------------- fp32 tiled GEMM for xproj (feeds GRU/context_loss, 2% threshold) ------------
__global__ __launch_bounds__(256) void gemm_nt_kernel(
    const float* __restrict__ A, const float* __restrict__ Bm,
    const float* __restrict__ bias, float* __restrict__ C,
    int M, int N, int K)
{
    __shared__ float a_s[16*64];
    __shared__ float b_s[16*64];
    const int tid = threadIdx.x;
    const int bn0 = blockIdx.x * 64;
    const int bm0 = blockIdx.y * 64;
    const int lr = tid >> 2;
    const int kq = (tid & 3) << 2;
    const int tx = tid & 15, ty = tid >> 4;
    float acc[4][4] = {};
    const float* Ap = A + (size_t)(bm0 + lr) * K + kq;
    const float* Bp = Bm + (size_t)(bn0 + lr) * K + kq;
    for (int kt = 0; kt < K; kt += 16) {
        float4 a = *(const float4*)(Ap + kt);
        float4 b = *(const float4*)(Bp + kt);
        __syncthreads();
        a_s[(kq+0)*64+lr] = a.x; a_s[(kq+1)*64+lr] = a.y;
        a_s[(kq+2)*64+lr] = a.z; a_s[(kq+3)*64+lr] = a.w;
        b_s[(kq+0)*64+lr] = b.x; b_s[(kq+1)*64+lr] = b.y;
        b_s[(kq+2)*64+lr] = b.z; b_s[(kq+3)*64+lr] = b.w;
        __syncthreads();
        #pragma unroll
        for (int kk = 0; kk < 16; kk++) {
            const float4 av = *(const float4*)&a_s[kk*64 + ty*4];
            const float4 bv = *(const float4*)&b_s[kk*64 + tx*4];
            const float aa[4] = {av.x, av.y, av.z, av.w};
            const float bb[4] = {bv.x, bv.y, bv.z, bv.w};
            #pragma unroll
            for (int i = 0; i < 4; i++)
                #pragma unroll
                for (int j = 0; j < 4; j++)
                    acc[i][j] = fmaf(aa[i], bb[j], acc[i][j]);
        }
    }
    const float4 b4 = *(const float4*)&bias[bn0 + tx*4];
    const float bc[4] = {b4.x, b4.y, b4.z, b4.w};
    #pragma unroll
    for (int i = 0; i < 4; i++) {
        *(float4*)&C[(size_t)(bm0 + ty*4 + i)*N + bn0 + tx*4] =
            make_float4(acc[i][0]+bc[0], acc[i][1]+bc[1], acc[i][2]+bc[2], acc[i][3]+bc[3]);
    }
}

// ---------------- GRU scan: 1024 threads/batch, whh held in registers ----------------
// Thread (j = tid&255, q = tid>>8) owns gate rows {j, 256+j, 512+j} over i in [64q, 64q+64).
// h broadcast from LDS (float4, same-address across wave -> free); partials reduced via LDS.
// Throughput floor: 196608 MAC/step / 128 FMA/cyc/CU = 1536 cyc/step -> ~330 us over 511 steps.
__global__ __launch_bounds__(1024) void gru_kernel(
    const float* __restrict__ XP, const float* __restrict__ WT,
    const float* __restrict__ bhh, const float* __restrict__ F,
    float* __restrict__ ctx_acc)
{
    __shared__ float hbuf[2][256];
    __shared__ float part[3][4][256];
    __shared__ float red[256];
    const int tid = threadIdx.x;
    const int b = blockIdx.x;
    const int j = tid & 255;
    const int q = tid >> 8;        // 0..3
    const int i0 = q << 6;
    // preload whh rows into registers: wr[u] = whh[j][i0+u] = WT[(i0+u)*768 + j]
    float wr[64], wz[64], wn[64];
    #pragma unroll
    for (int u = 0; u < 64; u++) {
        wr[u] = WT[(size_t)(i0+u)*768 + j];
        wz[u] = WT[(size_t)(i0+u)*768 + 256 + j];
        wn[u] = WT[(size_t)(i0+u)*768 + 512 + j];
    }
    if (tid < 256) hbuf[0][tid] = 0.0f;
    const float bb0 = bhh[j], bb1 = bhh[256+j], bb2 = bhh[512+j];
    float lsum = 0.0f;
    __syncthreads();
    int cur = 0;
    for (int t = 0; t < NT-1; t++) {
        // hoisted global loads (independent of h) — latency hidden behind phase A FMAs
        float xr=0.f, xz=0.f, xn=0.f, fv=0.f;
        if (tid < 256) {   // waves 0..3, wave-uniform branch
            const float* xp = XP + ((size_t)b*NT + t)*768;
            xr = xp[j]; xz = xp[256+j]; xn = xp[512+j];
            fv = F[((size_t)b*NT + t + 1)*NDCB + j];
        }
        // phase A: partial matvec over this thread's 64-wide i-chunk
        const float* hc = hbuf[cur];
        float a0 = 0.f, a1 = 0.f, a2 = 0.f;
        #pragma unroll
        for (int u4 = 0; u4 < 64; u4 += 4) {
            float4 hv = *(const float4*)&hc[i0 + u4];
            a0 = fmaf(wr[u4+0], hv.x, a0); a1 = fmaf(wz[u4+0], hv.x, a1); a2 = fmaf(wn[u4+0], hv.x, a2);
            a0 = fmaf(wr[u4+1], hv.y, a0); a1 = fmaf(wz[u4+1], hv.y, a1); a2 = fmaf(wn[u4+1], hv.y, a2);
            a0 = fmaf(wr[u4+2], hv.z, a0); a1 = fmaf(wz[u4+2], hv.z, a1); a2 = fmaf(wn[u4+2], hv.z, a2);
            a0 = fmaf(wr[u4+3], hv.w, a0); a1 = fmaf(wz[u4+3], hv.w, a1); a2 = fmaf(wn[u4+3], hv.w, a2);
        }
        part[0][q][j] = a0; part[1][q][j] = a1; part[2][q][j] = a2;
        __syncthreads();
        // phase B: gate nonlinearities + state update (waves 0..3 only)
        if (tid < 256) {
            float hprev = hc[j];
            float ghr = part[0][0][j] + part[0][1][j] + part[0][2][j] + part[0][3][j] + bb0;
            float ghz = part[1][0][j] + part[1][1][j] + part[1][2][j] + part[1][3][j] + bb1;
            float ghn = part[2][0][j] + part[2][1][j] + part[2][2][j] + part[2][3][j] + bb2;
            float r = 1.0f/(1.0f + __expf(-(xr + ghr)));
            float z = 1.0f/(1.0f + __expf(-(xz + ghz)));
            float v = fmaf(r, ghn, xn);
            v = fminf(fmaxf(v, -12.0f), 12.0f);          // clamped fast tanh
            float ev = __expf(-2.0f*v);
            float n = (1.0f - ev)/(1.0f + ev);
            float hnew = (1.0f - z)*n + z*hprev;
            float d = hnew - fv;
            lsum = fmaf(d, d, lsum);
            hbuf[cur^1][j] = hnew;
        }
        __syncthreads();   // protects hbuf[cur^1] reads and part[] overwrite next step
        cur ^= 1;
    }
    if (tid < 256) red[j] = lsum;
    __syncthreads();
    for (int off = 128; off > 0; off >>= 1) {
        if (tid < off) red[tid] += red[tid + off];
        __syncthreads();
    }
    if (tid == 0) atomicAdd(ctx_acc, red[0]);
}

// ---------------- small prep kernels ----------------
__global__ __launch_bounds__(256) void prep_kernel(
    const float* __restrict__ conv_w, float* __restrict__ w3,
    const float* __restrict__ whh, float* __restrict__ wht,
    float* __restrict__ accv)
{
    int e = blockIdx.x*256 + threadIdx.x;     // < 196608
    if (e == 0) { accv[0] = 0.0f; accv[1] = 0.0f; }
    {   // w3[k][c][i] = conv_w[c][i][k]
        int k = e >> 16;
        int r = e & 65535;
        int c = r >> 8, i = r & 255;
        w3[e] = conv_w[(size_t)c*768 + i*3 + k];
    }
    {   // wht[i][j] = whh[j][i]
        int i = e / 768, j = e - i*768;
        wht[e] = whh[(size_t)j*256 + i];
    }
}

// s_c = fl32(exact sum c^2) via fp64   [LOCKED numerics]
__global__ __launch_bounds__(64) void cnorm_kernel(
    const float* __restrict__ CB, float* __restrict__ cn)
{
    const int k = blockIdx.x;
    const int lane = threadIdx.x;
    float4 v = *(const float4*)&CB[(size_t)k*NDCB + lane*4];
    double s = (double)v.x*(double)v.x + (double)v.y*(double)v.y
             + (double)v.z*(double)v.z + (double)v.w*(double)v.w;
    #pragma unroll
    for (int off = 32; off > 0; off >>= 1) s += __shfl_down(s, off);
    if (lane == 0) cn[k] = (float)s;
}

__global__ void finalize_kernel(const float* __restrict__ acc, float* __restrict__ out)
{
    if (threadIdx.x == 0) {
        float msd = acc[0] * (1.0f/4194304.0f);   // mean over 32*512*256
        float ctx = acc[1] * (1.0f/4184064.0f);   // mean over 32*511*256
        out[0] = msd;                 // commitment_loss
        out[1] = msd;                 // codebook_loss (same forward value)
        out[2] = ctx;                 // context_loss
        out[3] = 1.25f*msd + 0.1f*ctx; // vq_loss
    }
}

extern "C" void kernel_launch(void* const* d_in, const int* in_sizes, int n_in,
                              void* d_out, int out_size, void* d_ws, size_t ws_size,
                              hipStream_t stream) {
    const float* x      = (const float*)d_in[0];
    const float* w1     = (const float*)d_in[1];
    const float* b1     = (const float*)d_in[2];
    const float* w2     = (const float*)d_in[3];
    const float* b2     = (const float*)d_in[4];
    const float* conv_w = (const float*)d_in[5];
    const float* conv_b = (const float*)d_in[6];
    const float* cb     = (const float*)d_in[7];
    const float* wih    = (const float*)d_in[8];
    const float* whh    = (const float*)d_in[9];
    const float* bih    = (const float*)d_in[10];
    const float* bhh    = (const float*)d_in[11];
    float* out = (float*)d_out;

    // workspace layout (regions re-used once dead):
    //   [0,        16.7M)  feat  (fp32)          conv -> gru
    //   [16.7M,    50.3M)  h1    (fp32)          gemm1 -> gemm2
    //   [16.7M,    67.1M)  xproj (fp32, 50.3MB)  gemm3 -> gru   (overlays dead h1+h2)
    //   [50.3M,    67.1M)  h2    (fp32)          gemm2 -> conv
    //   [67.1M, ...]       cn / w3 / wht / accv
    char* ws = (char*)d_ws;
    float*  feat   = (float*)(ws + 0);
    float*  h1     = (float*)(ws + 16777216);
    float*  xproj  = (float*)(ws + 16777216);
    float*  h2     = (float*)(ws + 50331648);
    float*  cn     = (float*)(ws + 67108864);
    float*  w3     = (float*)(ws + 67141632);
    float*  wht    = (float*)(ws + 67928064);
    float*  accv   = (float*)(ws + 68714496);

    float* idx_out = out;                   // 16384 indices (as float)
    float* qout    = out + 16384;           // 4,194,304 quantized
    float* louts   = out + 16384 + 4194304; // 4 scalars

    prep_kernel<<<768, 256, 0, stream>>>(conv_w, w3, whh, wht, accv);
    cnorm_kernel<<<NKCB, 64, 0, stream>>>(cb, cn);
    gemm_nt_f64_kernel<true ><<<dim3(NHMID/64, NROWS/64), 256, 0, stream>>>(x,  w1, b1, h1, NROWS, NHMID, NDIN);
    gemm_nt_f64_kernel<true ><<<dim3(NDCB/64,  NROWS/64), 256, 0, stream>>>(h1, w2, b2, h2, NROWS, NDCB, NHMID);
    conv3_f64_kernel<<<dim3(NDCB/64, NROWS/64), 256, 0, stream>>>(h2, w3, conv_b, feat);
    vq_kernel<<<NROWS/64, 512, 0, stream>>>(feat, cb, cn, idx_out, qout, accv);
    gemm_nt_kernel<<<dim3(768/64, NROWS/64), 256, 0, stream>>>(qout, wih, bih, xproj, NROWS, 768, NDCB);
    gru_kernel<<<NB, 1024, 0, stream>>>(xproj, wht, bhh, feat, accv + 1);
    finalize_kernel<<<1, 64, 0, stream>>>(accv, louts);
}

// Round 5
// 6923.959 us; speedup vs baseline: 1.1171x; 1.0060x over previous
//
#include <hip/hip_runtime.h>
#include <math.h>

#define NB 32
#define NT 512
#define NDIN 1024
#define NDCB 256
#define NKCB 8192
#define NHMID 512
#define NROWS (NB*NT)   // 16384

// ---------------- fp64-accumulate tiled GEMM: C = act(A(MxK) * B(NxK)^T + bias) ----------------
// fp32 in/out, fp64 accumulation: output = fl(exact), the canonical fp32 result.  [LOCKED numerics]
template<bool RELU>
__global__ __launch_bounds__(256) void gemm_nt_f64_kernel(
    const float* __restrict__ A, const float* __restrict__ Bm,
    const float* __restrict__ bias, float* __restrict__ C,
    int M, int N, int K)
{
    __shared__ double a_s[16*64];
    __shared__ double b_s[16*64];
    const int tid = threadIdx.x;
    const int bn0 = blockIdx.x * 64;
    const int bm0 = blockIdx.y * 64;
    const int lr = tid >> 2;          // 0..63
    const int kq = (tid & 3) << 2;    // 0,4,8,12
    const int tx = tid & 15, ty = tid >> 4;
    double acc[4][4] = {};
    const float* Ap = A + (size_t)(bm0 + lr) * K + kq;
    const float* Bp = Bm + (size_t)(bn0 + lr) * K + kq;
    for (int kt = 0; kt < K; kt += 16) {
        float4 a = *(const float4*)(Ap + kt);
        float4 b = *(const float4*)(Bp + kt);
        __syncthreads();
        a_s[(kq+0)*64+lr] = (double)a.x; a_s[(kq+1)*64+lr] = (double)a.y;
        a_s[(kq+2)*64+lr] = (double)a.z; a_s[(kq+3)*64+lr] = (double)a.w;
        b_s[(kq+0)*64+lr] = (double)b.x; b_s[(kq+1)*64+lr] = (double)b.y;
        b_s[(kq+2)*64+lr] = (double)b.z; b_s[(kq+3)*64+lr] = (double)b.w;
        __syncthreads();
        #pragma unroll
        for (int kk = 0; kk < 16; kk++) {
            double aa[4], bb[4];
            #pragma unroll
            for (int u = 0; u < 4; u++) { aa[u] = a_s[kk*64 + ty*4 + u]; bb[u] = b_s[kk*64 + tx*4 + u]; }
            #pragma unroll
            for (int i = 0; i < 4; i++)
                #pragma unroll
                for (int j = 0; j < 4; j++)
                    acc[i][j] = fma(aa[i], bb[j], acc[i][j]);
        }
    }
    const float4 b4 = *(const float4*)&bias[bn0 + tx*4];
    const double bc[4] = {(double)b4.x, (double)b4.y, (double)b4.z, (double)b4.w};
    #pragma unroll
    for (int i = 0; i < 4; i++) {
        float o[4];
        #pragma unroll
        for (int j = 0; j < 4; j++) {
            double v = acc[i][j] + bc[j];
            if (RELU) v = fmax(v, 0.0);
            o[j] = (float)v;
        }
        *(float4*)&C[(size_t)(bm0 + ty*4 + i)*N + bn0 + tx*4] =
            make_float4(o[0], o[1], o[2], o[3]);
    }
}

// ---------------- conv1d k=3 SAME, fp64 accumulation ----------------  [LOCKED numerics]
__global__ __launch_bounds__(256) void conv3_f64_kernel(
    const float* __restrict__ H2, const float* __restrict__ W3,
    const float* __restrict__ bias, float* __restrict__ F)
{
    __shared__ double a_s[16*68];       // [k][local row], local l <-> global bm0-1+l
    __shared__ double b_s[3][16*64];
    const int tid = threadIdx.x;
    const int bn0 = blockIdx.x * 64;
    const int bm0 = blockIdx.y * 64;
    const int lr = tid >> 2;
    const int kq = (tid & 3) << 2;
    const int tx = tid & 15, ty = tid >> 4;
    const int tmod = bm0 & (NT-1);
    const bool has_top = (tmod != 0);
    const bool has_bot = (tmod + 64 < NT);
    double acc[4][4] = {};
    for (int kt = 0; kt < NDCB; kt += 16) {
        float4 a = make_float4(0.f,0.f,0.f,0.f);
        if (lr >= 1 || has_top)
            a = *(const float4*)&H2[(size_t)(bm0 - 1 + lr)*NDCB + kt + kq];
        float4 e = make_float4(0.f,0.f,0.f,0.f);
        int l2 = 0, kq2 = 0;
        if (tid < 8) {
            l2 = 64 + (tid >> 2); kq2 = (tid & 3) << 2;
            if (l2 == 64 || has_bot)
                e = *(const float4*)&H2[(size_t)(bm0 - 1 + l2)*NDCB + kt + kq2];
        }
        float4 w[3];
        #pragma unroll
        for (int s = 0; s < 3; s++)
            w[s] = *(const float4*)&W3[(size_t)s*65536 + (size_t)(bn0 + lr)*NDCB + kt + kq];
        __syncthreads();
        a_s[(kq+0)*68+lr]=(double)a.x; a_s[(kq+1)*68+lr]=(double)a.y;
        a_s[(kq+2)*68+lr]=(double)a.z; a_s[(kq+3)*68+lr]=(double)a.w;
        if (tid < 8) {
            a_s[(kq2+0)*68+l2]=(double)e.x; a_s[(kq2+1)*68+l2]=(double)e.y;
            a_s[(kq2+2)*68+l2]=(double)e.z; a_s[(kq2+3)*68+l2]=(double)e.w;
        }
        #pragma unroll
        for (int s = 0; s < 3; s++) {
            b_s[s][(kq+0)*64+lr]=(double)w[s].x; b_s[s][(kq+1)*64+lr]=(double)w[s].y;
            b_s[s][(kq+2)*64+lr]=(double)w[s].z; b_s[s][(kq+3)*64+lr]=(double)w[s].w;
        }
        __syncthreads();
        #pragma unroll
        for (int kk = 0; kk < 16; kk++) {
            double aa[6];
            #pragma unroll
            for (int u = 0; u < 6; u++) aa[u] = a_s[kk*68 + ty*4 + u];
            #pragma unroll
            for (int s = 0; s < 3; s++) {
                double bb[4];
                #pragma unroll
                for (int u = 0; u < 4; u++) bb[u] = b_s[s][kk*64 + tx*4 + u];
                #pragma unroll
                for (int i = 0; i < 4; i++)
                    #pragma unroll
                    for (int j = 0; j < 4; j++)
                        acc[i][j] = fma(aa[i+s], bb[j], acc[i][j]);
            }
        }
    }
    const float4 b4 = *(const float4*)&bias[bn0 + tx*4];
    const double bc[4] = {(double)b4.x, (double)b4.y, (double)b4.z, (double)b4.w};
    #pragma unroll
    for (int i = 0; i < 4; i++) {
        const size_t base = (size_t)(bm0 + ty*4 + i)*NDCB + bn0 + tx*4;
        *(float4*)&F[base] = make_float4((float)(acc[i][0]+bc[0]), (float)(acc[i][1]+bc[1]),
                                         (float)(acc[i][2]+bc[2]), (float)(acc[i][3]+bc[3]));
    }
}

// ---------------- VQ: fp32 GEMM prefilter + canonical-fp32-quantized argmin on near-ties ----
// [LOCKED numerics] d2 = fl32( fl32( s_f - 2*G ) + s_c ), argmin with first-index tie-break.
__global__ __launch_bounds__(512) void vq_kernel(
    const float* __restrict__ F, const float* __restrict__ CB,
    const float* __restrict__ cnorm, float* __restrict__ idx_out,
    float* __restrict__ qout, float* __restrict__ msd_acc)
{
    __shared__ float a_s[32*64];     // [k][row]   8 KB
    __shared__ float b_s[32*128];    // [k][col]  16 KB
    __shared__ float red_v[64*64];   // top-2 per (row, tx); reused for msd reduce
    __shared__ int   red_i[64*64];
    __shared__ int   bests[64];
    __shared__ int   cand[64][12];
    __shared__ int   ccnt[64];
    const int tid = threadIdx.x;
    const int m0 = blockIdx.x * 64;
    const int tx = tid & 31, ty = tid >> 5;   // 32 x 16
    float mv1[4], mv2[4]; int mi1[4], mi2[4];
    #pragma unroll
    for (int i = 0; i < 4; i++) { mv1[i]=3.0e38f; mv2[i]=3.0e38f; mi1[i]=0x7fffffff; mi2[i]=0x7fffffff; }
    const int ar  = tid >> 3;            // 0..63
    const int akq = (tid & 7) << 2;      // 0..28
    for (int n0 = 0; n0 < NKCB; n0 += 128) {
        float dot[4][4] = {};
        for (int kt = 0; kt < NDCB; kt += 32) {
            __syncthreads();
            {
                float4 a = *(const float4*)&F[(size_t)(m0 + ar)*NDCB + kt + akq];
                a_s[(akq+0)*64+ar]=a.x; a_s[(akq+1)*64+ar]=a.y;
                a_s[(akq+2)*64+ar]=a.z; a_s[(akq+3)*64+ar]=a.w;
            }
            #pragma unroll
            for (int u = 0; u < 2; u++) {
                int e2 = tid + u*512;
                int c = e2 >> 3, kqb = (e2 & 7) << 2;
                float4 b = *(const float4*)&CB[(size_t)(n0 + c)*NDCB + kt + kqb];
                b_s[(kqb+0)*128+c]=b.x; b_s[(kqb+1)*128+c]=b.y;
                b_s[(kqb+2)*128+c]=b.z; b_s[(kqb+3)*128+c]=b.w;
            }
            __syncthreads();
            #pragma unroll
            for (int kk = 0; kk < 32; kk++) {
                const float4 av = *(const float4*)&a_s[kk*64 + ty*4];
                const float4 bv = *(const float4*)&b_s[kk*128 + tx*4];
                const float aa[4]={av.x,av.y,av.z,av.w};
                const float bb[4]={bv.x,bv.y,bv.z,bv.w};
                #pragma unroll
                for (int i=0;i<4;i++)
                    #pragma unroll
                    for (int j=0;j<4;j++)
                        dot[i][j] = fmaf(aa[i], bb[j], dot[i][j]);
            }
        }
        #pragma unroll
        for (int j = 0; j < 4; j++) {
            const int col = n0 + tx*4 + j;
            const float cn = cnorm[col];
            #pragma unroll
            for (int i = 0; i < 4; i++) {
                float s = fmaf(-2.0f, dot[i][j], cn);
                if (s < mv1[i]) { mv2[i]=mv1[i]; mi2[i]=mi1[i]; mv1[i]=s; mi1[i]=col; }
                else if (s < mv2[i]) { mv2[i]=s; mi2[i]=col; }
            }
        }
    }
    #pragma unroll
    for (int i = 0; i < 4; i++) {
        const int row = ty*4 + i;
        red_v[row*64 + tx*2 + 0] = mv1[i]; red_i[row*64 + tx*2 + 0] = mi1[i];
        red_v[row*64 + tx*2 + 1] = mv2[i]; red_i[row*64 + tx*2 + 1] = mi2[i];
    }
    __syncthreads();
    if (tid < 64) {
        float bv = 3.0e38f; int bi = 0x7fffffff;
        for (int e = 0; e < 64; e++) {
            float v = red_v[tid*64 + e]; int ii = red_i[tid*64 + e];
            if (v < bv || (v == bv && ii < bi)) { bv = v; bi = ii; }
        }
        int cnt = 0;
        for (int e = 0; e < 64; e++) {
            if (red_v[tid*64 + e] < bv + 1.0e-6f) {
                if (cnt < 12) cand[tid][cnt] = red_i[tid*64 + e];
                cnt++;
            }
        }
        bests[tid] = bi;
        ccnt[tid] = (cnt > 12) ? 12 : cnt;
    }
    __syncthreads();
    // Canonical fp32-quantized rescore of near-tie rows (one wave per row, round-robin).
    {
        const int wid = tid >> 6, lane = tid & 63;
        for (int r = wid; r < 64; r += 8) {
            const int nc = ccnt[r];
            if (nc < 2) continue;
            double sf = 0.0;
            #pragma unroll
            for (int u = 0; u < 4; u++) {
                double fv = (double)F[(size_t)(m0+r)*NDCB + lane*4 + u];
                sf = fma(fv, fv, sf);
            }
            #pragma unroll
            for (int off = 32; off > 0; off >>= 1) sf += __shfl_down(sf, off);
            const float sf32 = (float)sf;          // valid on lane 0
            float bd2 = 0.0f; int bidx = 0x7fffffff;
            for (int c = 0; c < nc; c++) {
                const int k = cand[r][c];
                double g = 0.0;
                #pragma unroll
                for (int u = 0; u < 4; u++) {
                    double cv = (double)CB[(size_t)k*NDCB + lane*4 + u];
                    double fv = (double)F[(size_t)(m0+r)*NDCB + lane*4 + u];
                    g = fma(cv, fv, g);
                }
                #pragma unroll
                for (int off = 32; off > 0; off >>= 1) g += __shfl_down(g, off);
                if (lane == 0) {
                    const float G32 = (float)g;
                    const float t  = sf32 - 2.0f*G32;
                    const float d2 = t + cnorm[k];
                    if (c == 0 || d2 < bd2 || (d2 == bd2 && k < bidx)) { bd2 = d2; bidx = k; }
                }
            }
            if (lane == 0) bests[r] = bidx;
        }
    }
    __syncthreads();
    if (tid < 64) idx_out[m0 + tid] = (float)bests[tid];
    float lsum = 0.0f;
    #pragma unroll
    for (int s = 0; s < 8; s++) {
        int e = tid + s*512;
        int row = e >> 6, kqe = (e & 63) << 2;
        float4 q = *(const float4*)&CB[(size_t)bests[row]*NDCB + kqe];
        float4 f = *(const float4*)&F[(size_t)(m0+row)*NDCB + kqe];
        float dx=f.x-q.x, dy=f.y-q.y, dz=f.z-q.z, dw=f.w-q.w;
        lsum += dx*dx + dy*dy + dz*dz + dw*dw;
        *(float4*)&qout[(size_t)(m0+row)*NDCB + kqe] = q;
    }
    red_v[tid] = lsum;
    __syncthreads();
    for (int off = 256; off > 0; off >>= 1) {
        if (tid < off) red_v[tid] += red_v[tid + off];
        __syncthreads();
    }
    if (tid == 0) atomicAdd(msd_acc, red_v[0]);
}

// ---------------- fp32 tiled GEMM for xproj (feeds GRU/context_loss, 2% threshold) ------------
__global__ __launch_bounds__(256) void gemm_nt_kernel(
    const float* __restrict__ A, const float* __restrict__ Bm,
    const float* __restrict__ bias, float* __restrict__ C,
    int M, int N, int K)
{
    __shared__ float a_s[16*64];
    __shared__ float b_s[16*64];
    const int tid = threadIdx.x;
    const int bn0 = blockIdx.x * 64;
    const int bm0 = blockIdx.y * 64;
    const int lr = tid >> 2;
    const int kq = (tid & 3) << 2;
    const int tx = tid & 15, ty = tid >> 4;
    float acc[4][4] = {};
    const float* Ap = A + (size_t)(bm0 + lr) * K + kq;
    const float* Bp = Bm + (size_t)(bn0 + lr) * K + kq;
    for (int kt = 0; kt < K; kt += 16) {
        float4 a = *(const float4*)(Ap + kt);
        float4 b = *(const float4*)(Bp + kt);
        __syncthreads();
        a_s[(kq+0)*64+lr] = a.x; a_s[(kq+1)*64+lr] = a.y;
        a_s[(kq+2)*64+lr] = a.z; a_s[(kq+3)*64+lr] = a.w;
        b_s[(kq+0)*64+lr] = b.x; b_s[(kq+1)*64+lr] = b.y;
        b_s[(kq+2)*64+lr] = b.z; b_s[(kq+3)*64+lr] = b.w;
        __syncthreads();
        #pragma unroll
        for (int kk = 0; kk < 16; kk++) {
            const float4 av = *(const float4*)&a_s[kk*64 + ty*4];
            const float4 bv = *(const float4*)&b_s[kk*64 + tx*4];
            const float aa[4] = {av.x, av.y, av.z, av.w};
            const float bb[4] = {bv.x, bv.y, bv.z, bv.w};
            #pragma unroll
            for (int i = 0; i < 4; i++)
                #pragma unroll
                for (int j = 0; j < 4; j++)
                    acc[i][j] = fmaf(aa[i], bb[j], acc[i][j]);
        }
    }
    const float4 b4 = *(const float4*)&bias[bn0 + tx*4];
    const float bc[4] = {b4.x, b4.y, b4.z, b4.w};
    #pragma unroll
    for (int i = 0; i < 4; i++) {
        *(float4*)&C[(size_t)(bm0 + ty*4 + i)*N + bn0 + tx*4] =
            make_float4(acc[i][0]+bc[0], acc[i][1]+bc[1], acc[i][2]+bc[2], acc[i][3]+bc[3]);
    }
}

// ---------------- GRU scan: 1024 threads/batch, whh resident in registers ----------------
// __launch_bounds__(1024, 4): 16 waves = 4 waves/EU = 1 block/CU -> VGPR cap 512/thread,
// enough for 48 float4 weight registers (192 VGPR) + working set. R4's (1024) default
// capped VGPR at 64 and spilled the weights to scratch (WRITE_SIZE 11.6MB, 4.4ms).
// Thread (j = tid&255, q = tid>>8) owns gate rows {j, 256+j, 512+j} over i in [64q, 64q+64).
// h broadcast from LDS (wave-uniform address -> conflict-free); partials reduced via LDS.
__global__ __launch_bounds__(1024, 4) void gru_kernel(
    const float* __restrict__ XP, const float* __restrict__ WT,
    const float* __restrict__ bhh, const float* __restrict__ F,
    float* __restrict__ ctx_acc)
{
    __shared__ float hbuf[2][256];
    __shared__ float part[3][4][256];
    __shared__ float red[256];
    const int tid = threadIdx.x;
    const int b = blockIdx.x;
    const int j = tid & 255;
    const int q = tid >> 8;        // 0..3
    const int i0 = q << 6;
    // preload whh into registers: wr[k].{x,y,z,w} = whh[j][i0+4k+{0..3}] = WT[(i0+4k+u)*768 + j]
    float4 wr[16], wz[16], wn[16];
    #pragma unroll
    for (int k = 0; k < 16; k++) {
        const float* base = WT + (size_t)(i0 + 4*k)*768 + j;
        wr[k] = make_float4(base[0],       base[768],       base[1536],       base[2304]);
        wz[k] = make_float4(base[256],     base[256+768],   base[256+1536],   base[256+2304]);
        wn[k] = make_float4(base[512],     base[512+768],   base[512+1536],   base[512+2304]);
    }
    if (tid < 256) hbuf[0][tid] = 0.0f;
    const float bb0 = bhh[j], bb1 = bhh[256+j], bb2 = bhh[512+j];
    float lsum = 0.0f;
    __syncthreads();
    int cur = 0;
    for (int t = 0; t < NT-1; t++) {
        // hoisted global loads (independent of h) — latency hidden behind phase A FMAs
        float xr=0.f, xz=0.f, xn=0.f, fv=0.f;
        if (tid < 256) {   // waves 0..3, wave-uniform branch
            const float* xp = XP + ((size_t)b*NT + t)*768;
            xr = xp[j]; xz = xp[256+j]; xn = xp[512+j];
            fv = F[((size_t)b*NT + t + 1)*NDCB + j];
        }
        // phase A: partial matvec over this thread's 64-wide i-chunk (192 FMA, all registers)
        const float* hc = hbuf[cur];
        float a0 = 0.f, a1 = 0.f, a2 = 0.f;
        #pragma unroll
        for (int k = 0; k < 16; k++) {
            float4 hv = *(const float4*)&hc[i0 + 4*k];
            a0 = fmaf(wr[k].x, hv.x, a0); a1 = fmaf(wz[k].x, hv.x, a1); a2 = fmaf(wn[k].x, hv.x, a2);
            a0 = fmaf(wr[k].y, hv.y, a0); a1 = fmaf(wz[k].y, hv.y, a1); a2 = fmaf(wn[k].y, hv.y, a2);
            a0 = fmaf(wr[k].z, hv.z, a0); a1 = fmaf(wz[k].z, hv.z, a1); a2 = fmaf(wn[k].z, hv.z, a2);
            a0 = fmaf(wr[k].w, hv.w, a0); a1 = fmaf(wz[k].w, hv.w, a1); a2 = fmaf(wn[k].w, hv.w, a2);
        }
        part[0][q][j] = a0; part[1][q][j] = a1; part[2][q][j] = a2;
        __syncthreads();
        // phase B: gate nonlinearities + state update (waves 0..3 only)
        if (tid < 256) {
            float hprev = hc[j];
            float ghr = part[0][0][j] + part[0][1][j] + part[0][2][j] + part[0][3][j] + bb0;
            float ghz = part[1][0][j] + part[1][1][j] + part[1][2][j] + part[1][3][j] + bb1;
            float ghn = part[2][0][j] + part[2][1][j] + part[2][2][j] + part[2][3][j] + bb2;
            float r = 1.0f/(1.0f + __expf(-(xr + ghr)));
            float z = 1.0f/(1.0f + __expf(-(xz + ghz)));
            float v = fmaf(r, ghn, xn);
            v = fminf(fmaxf(v, -12.0f), 12.0f);          // clamped fast tanh
            float ev = __expf(-2.0f*v);
            float n = (1.0f - ev)/(1.0f + ev);
            float hnew = (1.0f - z)*n + z*hprev;
            float d = hnew - fv;
            lsum = fmaf(d, d, lsum);
            hbuf[cur^1][j] = hnew;
        }
        __syncthreads();   // protects hbuf[cur^1] reads and part[] overwrite next step
        cur ^= 1;
    }
    if (tid < 256) red[j] = lsum;
    __syncthreads();
    for (int off = 128; off > 0; off >>= 1) {
        if (tid < off) red[tid] += red[tid + off];
        __syncthreads();
    }
    if (tid == 0) atomicAdd(ctx_acc, red[0]);
}

// ---------------- small prep kernels ----------------
__global__ __launch_bounds__(256) void prep_kernel(
    const float* __restrict__ conv_w, float* __restrict__ w3,
    const float* __restrict__ whh, float* __restrict__ wht,
    float* __restrict__ accv)
{
    int e = blockIdx.x*256 + threadIdx.x;     // < 196608
    if (e == 0) { accv[0] = 0.0f; accv[1] = 0.0f; }
    {   // w3[k][c][i] = conv_w[c][i][k]
        int k = e >> 16;
        int r = e & 65535;
        int c = r >> 8, i = r & 255;
        w3[e] = conv_w[(size_t)c*768 + i*3 + k];
    }
    {   // wht[i][j] = whh[j][i]
        int i = e / 768, j = e - i*768;
        wht[e] = whh[(size_t)j*256 + i];
    }
}

// s_c = fl32(exact sum c^2) via fp64   [LOCKED numerics]
__global__ __launch_bounds__(64) void cnorm_kernel(
    const float* __restrict__ CB, float* __restrict__ cn)
{
    const int k = blockIdx.x;
    const int lane = threadIdx.x;
    float4 v = *(const float4*)&CB[(size_t)k*NDCB + lane*4];
    double s = (double)v.x*(double)v.x + (double)v.y*(double)v.y
             + (double)v.z*(double)v.z + (double)v.w*(double)v.w;
    #pragma unroll
    for (int off = 32; off > 0; off >>= 1) s += __shfl_down(s, off);
    if (lane == 0) cn[k] = (float)s;
}

__global__ void finalize_kernel(const float* __restrict__ acc, float* __restrict__ out)
{
    if (threadIdx.x == 0) {
        float msd = acc[0] * (1.0f/4194304.0f);   // mean over 32*512*256
        float ctx = acc[1] * (1.0f/4184064.0f);   // mean over 32*511*256
        out[0] = msd;                 // commitment_loss
        out[1] = msd;                 // codebook_loss (same forward value)
        out[2] = ctx;                 // context_loss
        out[3] = 1.25f*msd + 0.1f*ctx; // vq_loss
    }
}

extern "C" void kernel_launch(void* const* d_in, const int* in_sizes, int n_in,
                              void* d_out, int out_size, void* d_ws, size_t ws_size,
                              hipStream_t stream) {
    const float* x      = (const float*)d_in[0];
    const float* w1     = (const float*)d_in[1];
    const float* b1     = (const float*)d_in[2];
    const float* w2     = (const float*)d_in[3];
    const float* b2     = (const float*)d_in[4];
    const float* conv_w = (const float*)d_in[5];
    const float* conv_b = (const float*)d_in[6];
    const float* cb     = (const float*)d_in[7];
    const float* wih    = (const float*)d_in[8];
    const float* whh    = (const float*)d_in[9];
    const float* bih    = (const float*)d_in[10];
    const float* bhh    = (const float*)d_in[11];
    float* out = (float*)d_out;

    // workspace layout (regions re-used once dead):
    //   [0,        16.7M)  feat  (fp32)          conv -> gru
    //   [16.7M,    50.3M)  h1    (fp32)          gemm1 -> gemm2
    //   [16.7M,    67.1M)  xproj (fp32, 50.3MB)  gemm3 -> gru   (overlays dead h1+h2)
    //   [50.3M,    67.1M)  h2    (fp32)          gemm2 -> conv
    //   [67.1M, ...]       cn / w3 / wht / accv
    char* ws = (char*)d_ws;
    float*  feat   = (float*)(ws + 0);
    float*  h1     = (float*)(ws + 16777216);
    float*  xproj  = (float*)(ws + 16777216);
    float*  h2     = (float*)(ws + 50331648);
    float*  cn     = (float*)(ws + 67108864);
    float*  w3     = (float*)(ws + 67141632);
    float*  wht    = (float*)(ws + 67928064);
    float*  accv   = (float*)(ws + 68714496);

    float* idx_out = out;                   // 16384 indices (as float)
    float* qout    = out + 16384;           // 4,194,304 quantized
    float* louts   = out + 16384 + 4194304; // 4 scalars

    prep_kernel<<<768, 256, 0, stream>>>(conv_w, w3, whh, wht, accv);
    cnorm_kernel<<<NKCB, 64, 0, stream>>>(cb, cn);
    gemm_nt_f64_kernel<true ><<<dim3(NHMID/64, NROWS/64), 256, 0, stream>>>(x,  w1, b1, h1, NROWS, NHMID, NDIN);
    gemm_nt_f64_kernel<true ><<<dim3(NDCB/64,  NROWS/64), 256, 0, stream>>>(h1, w2, b2, h2, NROWS, NDCB, NHMID);
    conv3_f64_kernel<<<dim3(NDCB/64, NROWS/64), 256, 0, stream>>>(h2, w3, conv_b, feat);
    vq_kernel<<<NROWS/64, 512, 0, stream>>>(feat, cb, cn, idx_out, qout, accv);
    gemm_nt_kernel<<<dim3(768/64, NROWS/64), 256, 0, stream>>>(qout, wih, bih, xproj, NROWS, 768, NDCB);
    gru_kernel<<<NB, 1024, 0, stream>>>(xproj, wht, bhh, feat, accv + 1);
    finalize_kernel<<<1, 64, 0, stream>>>(accv, louts);
}